// Round 1
// baseline (128.755 us; speedup 1.0000x reference)
//
#include <hip/hip_runtime.h>

#define NRAD 16
#define LL   34
#define NLAM 4
#define CH   8

__global__ void zero_counts_kernel(int* counts, int nat) {
    int i = blockIdx.x * blockDim.x + threadIdx.x;
    if (i < nat) counts[i] = 0;
}

__global__ void hist_kernel(const int* __restrict__ idx, int* __restrict__ counts, int npairs) {
    int p = blockIdx.x * blockDim.x + threadIdx.x;
    if (p < npairs) atomicAdd(&counts[idx[p]], 1);
}

// Single-block exclusive prefix sum over counts[nat]; writes offsets[0..nat]
// and turns counts[] into the scatter cursor (== offsets).
__global__ __launch_bounds__(1024) void prefix_kernel(int* __restrict__ counts,
                                                      int* __restrict__ offsets,
                                                      int nat, int npairs) {
    __shared__ int sh[1024];
    __shared__ int carry_sh;
    int tid = threadIdx.x;
    if (tid == 0) carry_sh = 0;
    __syncthreads();
    for (int base = 0; base < nat; base += 1024) {
        int i = base + tid;
        int v = (i < nat) ? counts[i] : 0;
        sh[tid] = v;
        __syncthreads();
        for (int off = 1; off < 1024; off <<= 1) {
            int t = (tid >= off) ? sh[tid - off] : 0;
            __syncthreads();
            sh[tid] += t;
            __syncthreads();
        }
        int carry = carry_sh;
        int excl  = sh[tid] - v + carry;
        if (i < nat) { offsets[i] = excl; counts[i] = excl; }
        __syncthreads();
        if (tid == 0) carry_sh = carry + sh[1023];
        __syncthreads();
    }
    if (tid == 0) offsets[nat] = npairs;
}

__global__ void scatter_kernel(const int* __restrict__ idx, int* __restrict__ cursor,
                               int* __restrict__ perm, int npairs) {
    int p = blockIdx.x * blockDim.x + threadIdx.x;
    if (p < npairs) {
        int a   = idx[p];
        int pos = atomicAdd(&cursor[a], 1);
        perm[pos] = p;
    }
}

// One block per atom: accumulate G[r][l] = sum_pairs radial[p,r]*g[p,l] in
// registers (thread owns r=tid>>4, l in {sub, sub+16, sub+32}), then epilogue
// out[atom,r,z] = sum_l G^2 * fact[l] * lambda_z^{s_l} * 2^{1-zeta}.
__global__ __launch_bounds__(256) void reduce_kernel(
    const float* __restrict__ rij_unit,
    const float* __restrict__ radial,
    const float* __restrict__ lambda_w,
    const int*   __restrict__ lxlylz,
    const int*   __restrict__ lsum,
    const float* __restrict__ fact,
    const int*   __restrict__ offsets,
    const int*   __restrict__ perm,
    const int*   __restrict__ z_ptr,
    float*       __restrict__ out)
{
    __shared__ float u_sh[CH][3];
    __shared__ float g_sh[CH][LL];
    __shared__ float rad_sh[CH][NRAD];
    __shared__ int   p_sh[CH];
    __shared__ int   l_sh[LL][3];
    __shared__ float f_sh[LL];
    __shared__ int   s_sh[LL];
    __shared__ float lam_sh[NLAM];
    __shared__ float lamp_sh[NLAM][LL];

    int tid = threadIdx.x;
    if (tid < LL) {
        l_sh[tid][0] = lxlylz[tid * 3 + 0];
        l_sh[tid][1] = lxlylz[tid * 3 + 1];
        l_sh[tid][2] = lxlylz[tid * 3 + 2];
        f_sh[tid]    = fact[tid];
        s_sh[tid]    = lsum[tid];
    }
    if (tid < NLAM) lam_sh[tid] = lambda_w[tid];
    __syncthreads();
    if (tid < NLAM * LL) {
        int z = tid / LL, l = tid - z * LL;
        float w = lam_sh[z];
        int   s = s_sh[l];
        float p = 1.f;
        for (int i = 0; i < s; ++i) p *= w;   // integer power: w may be negative
        lamp_sh[z][l] = p;
    }
    __syncthreads();

    int atom = blockIdx.x;
    int beg = offsets[atom], end = offsets[atom + 1];
    int r   = tid >> 4;
    int sub = tid & 15;
    int l0 = sub, l1 = sub + 16, l2 = sub + 32;   // l2 valid only for sub<2

    float acc0 = 0.f, acc1 = 0.f, acc2 = 0.f;

    for (int base = beg; base < end; base += CH) {
        int n = min(CH, end - base);
        if (tid < n) p_sh[tid] = perm[base + tid];
        __syncthreads();
        if (tid < n * 3) {
            int q = tid / 3, c = tid - q * 3;
            u_sh[q][c] = rij_unit[p_sh[q] * 3 + c] + 1e-12f;
        }
        {
            int t2 = tid - 32;
            if (t2 >= 0 && t2 < n * NRAD) {
                int q = t2 >> 4, rr = t2 & 15;
                rad_sh[q][rr] = radial[p_sh[q] * NRAD + rr];
            }
        }
        __syncthreads();
        for (int t = tid; t < n * LL; t += 256) {
            int q = t / LL, l = t - q * LL;
            float ux = u_sh[q][0], uy = u_sh[q][1], uz = u_sh[q][2];
            int lx = l_sh[l][0], ly = l_sh[l][1], lz = l_sh[l][2];
            float g = 1.f;
            for (int i = 0; i < lx; ++i) g *= ux;
            for (int i = 0; i < ly; ++i) g *= uy;
            for (int i = 0; i < lz; ++i) g *= uz;
            g_sh[q][l] = g;
        }
        __syncthreads();
        for (int q = 0; q < n; ++q) {
            float rad = rad_sh[q][r];
            acc0 += rad * g_sh[q][l0];
            acc1 += rad * g_sh[q][l1];
            if (sub < 2) acc2 += rad * g_sh[q][l2];
        }
        __syncthreads();
    }

    float scale = exp2f(1.0f - (float)z_ptr[0]);

    float o0, o1, o2, o3;
    float v = acc0 * acc0 * f_sh[l0];
    o0 = v * lamp_sh[0][l0]; o1 = v * lamp_sh[1][l0];
    o2 = v * lamp_sh[2][l0]; o3 = v * lamp_sh[3][l0];
    v = acc1 * acc1 * f_sh[l1];
    o0 += v * lamp_sh[0][l1]; o1 += v * lamp_sh[1][l1];
    o2 += v * lamp_sh[2][l1]; o3 += v * lamp_sh[3][l1];
    if (sub < 2) {
        v = acc2 * acc2 * f_sh[l2];
        o0 += v * lamp_sh[0][l2]; o1 += v * lamp_sh[1][l2];
        o2 += v * lamp_sh[2][l2]; o3 += v * lamp_sh[3][l2];
    }
#pragma unroll
    for (int m = 1; m < 16; m <<= 1) {
        o0 += __shfl_xor(o0, m, 16);
        o1 += __shfl_xor(o1, m, 16);
        o2 += __shfl_xor(o2, m, 16);
        o3 += __shfl_xor(o3, m, 16);
    }
    if (sub == 0) {
        float* op = out + ((size_t)atom * NRAD + r) * NLAM;
        op[0] = o0 * scale; op[1] = o1 * scale;
        op[2] = o2 * scale; op[3] = o3 * scale;
    }
}

extern "C" void kernel_launch(void* const* d_in, const int* in_sizes, int n_in,
                              void* d_out, int out_size, void* d_ws, size_t ws_size,
                              hipStream_t stream) {
    const int*   z_ptr    = (const int*)  d_in[0];
    const float* rij_unit = (const float*)d_in[2];
    const float* radial   = (const float*)d_in[3];
    const int*   atom_idx = (const int*)  d_in[4];
    const float* lambda_w = (const float*)d_in[5];
    const int*   lxlylz   = (const int*)  d_in[6];
    const int*   lsum     = (const int*)  d_in[7];
    const float* fact     = (const float*)d_in[8];

    const int npairs = in_sizes[4];
    const int nat    = out_size / (NRAD * NLAM);

    int* counts  = (int*)d_ws;            // nat ints (becomes cursor)
    int* offsets = counts + nat;          // nat+1 ints
    int* perm    = offsets + nat + 1;     // npairs ints

    zero_counts_kernel<<<(nat + 255) / 256, 256, 0, stream>>>(counts, nat);
    hist_kernel<<<(npairs + 255) / 256, 256, 0, stream>>>(atom_idx, counts, npairs);
    prefix_kernel<<<1, 1024, 0, stream>>>(counts, offsets, nat, npairs);
    scatter_kernel<<<(npairs + 255) / 256, 256, 0, stream>>>(atom_idx, counts, perm, npairs);
    reduce_kernel<<<nat, 256, 0, stream>>>(rij_unit, radial, lambda_w, lxlylz,
                                           lsum, fact, offsets, perm, z_ptr,
                                           (float*)d_out);
}

// Round 2
// 97.582 us; speedup vs baseline: 1.3195x; 1.3195x over previous
//
#include <hip/hip_runtime.h>

#define NRAD 16
#define LL   34
#define NLAM 4

__global__ void hist_kernel(const int* __restrict__ idx, int* __restrict__ counts, int npairs) {
    int p = blockIdx.x * blockDim.x + threadIdx.x;
    if (p < npairs) atomicAdd(&counts[idx[p]], 1);
}

// 1-block scan: 16 elems/thread in registers, wave shuffle-scan, 2 barriers.
__global__ __launch_bounds__(1024) void prefix_kernel(int* __restrict__ counts,
                                                      int* __restrict__ offsets,
                                                      int nat, int npairs) {
    const int PT = 16;  // 1024*16 = 16384 >= nat
    __shared__ int wsum[16];
    int tid = threadIdx.x, lane = tid & 63, w = tid >> 6;
    int base = tid * PT;
    int c[PT];
    int s = 0;
#pragma unroll
    for (int k = 0; k < PT; ++k) {
        int i = base + k;
        c[k] = (i < nat) ? counts[i] : 0;
        s += c[k];
    }
    int incl = s;
#pragma unroll
    for (int off = 1; off < 64; off <<= 1) {
        int v = __shfl_up(incl, off);
        if (lane >= off) incl += v;
    }
    if (lane == 63) wsum[w] = incl;
    __syncthreads();
    if (tid == 0) {
        int run = 0;
        for (int i = 0; i < 16; ++i) { int t = wsum[i]; wsum[i] = run; run += t; }
    }
    __syncthreads();
    int excl = wsum[w] + incl - s;   // exclusive prefix of this thread's first elem
#pragma unroll
    for (int k = 0; k < PT; ++k) {
        int i = base + k;
        if (i < nat) { offsets[i] = excl; counts[i] = excl; }
        excl += c[k];
    }
    if (tid == 0) offsets[nat] = npairs;
}

__global__ void scatter_kernel(const int* __restrict__ idx, int* __restrict__ cursor,
                               int* __restrict__ perm, int npairs) {
    int p = blockIdx.x * blockDim.x + threadIdx.x;
    if (p < npairs) {
        int a   = idx[p];
        int pos = atomicAdd(&cursor[a], 1);
        perm[pos] = p;
    }
}

__device__ __forceinline__ float powi4(float u, int e) {
    // u^e for e in [0,4], branchless-ish, no runtime-indexed arrays
    float r  = (e & 1) ? u : 1.0f;
    float u2 = u * u;
    if (e & 2) r *= u2;
    if (e & 4) r *= u2 * u2;
    return r;
}

// One wave per atom. Lane: r = lane>>2 (radial ch), c = lane&3.
// Lane accumulates G[r][l] for l in {8c..8c+7} (+ l=32+c for c<2).
// Monomial for l=lane computed by lane `lane`, redistributed via shuffles.
__global__ __launch_bounds__(256) void reduce_kernel(
    const float* __restrict__ rij,
    const float* __restrict__ radial,
    const float* __restrict__ lambda_w,
    const int*   __restrict__ lxlylz,
    const int*   __restrict__ lsum,
    const float* __restrict__ fact,
    const int*   __restrict__ offsets,
    const int*   __restrict__ perm,
    const int*   __restrict__ z_ptr,
    float*       __restrict__ out,
    int nat)
{
    __shared__ float coeff_sh[NLAM][LL];

    int tid = threadIdx.x;
    if (tid < NLAM * LL) {
        int z = tid / LL, l = tid - z * LL;
        float w = lambda_w[z];
        int   s = lsum[l];
        float pw = 1.0f;
        for (int i = 0; i < s; ++i) pw *= w;   // integer power: w may be negative
        coeff_sh[z][l] = pw * fact[l];
    }
    __syncthreads();

    int lane = tid & 63, wv = tid >> 6;
    int atom = blockIdx.x * 4 + wv;
    if (atom >= nat) return;

    int r = lane >> 2, c = lane & 3;
    int b = c << 3;

    // exponents for this lane's source monomial (l = lane)
    int elx = 0, ely = 0, elz = 0;
    if (lane < LL) {
        elx = lxlylz[lane * 3 + 0];
        ely = lxlylz[lane * 3 + 1];
        elz = lxlylz[lane * 3 + 2];
    }

    int beg = offsets[atom], end = offsets[atom + 1];

    float a[8];
#pragma unroll
    for (int j = 0; j < 8; ++j) a[j] = 0.0f;
    float aX = 0.0f;

    for (int base = beg; base < end; base += 64) {
        int ii = base + lane;
        int pv = (ii < end) ? perm[ii] : 0;
        int nn = min(64, end - base);
#pragma unroll 2
        for (int i = 0; i < nn; ++i) {
            int p = __shfl(pv, i);
            float ux = rij[p * 3 + 0] + 1e-12f;
            float uy = rij[p * 3 + 1] + 1e-12f;
            float uz = rij[p * 3 + 2] + 1e-12f;
            float rad = radial[(p << 4) + r];
            float m = powi4(ux, elx) * powi4(uy, ely) * powi4(uz, elz);
#pragma unroll
            for (int j = 0; j < 8; ++j)
                a[j] += rad * __shfl(m, b + j);
            float gE = __shfl(m, 32 + c);
            aX += (c < 2) ? rad * gE : 0.0f;
        }
    }

    float q[8];
#pragma unroll
    for (int j = 0; j < 8; ++j) q[j] = a[j] * a[j];
    float qX = aX * aX;

    float pz[NLAM];
#pragma unroll
    for (int z = 0; z < NLAM; ++z) {
        float acc = 0.0f;
#pragma unroll
        for (int j = 0; j < 8; ++j)
            acc += coeff_sh[z][b + j] * q[j];
        float ce = (c < 2) ? coeff_sh[z][32 + c] : 0.0f;
        acc += ce * qX;
        pz[z] = acc;
    }
#pragma unroll
    for (int z = 0; z < NLAM; ++z) {
        pz[z] += __shfl_xor(pz[z], 1);
        pz[z] += __shfl_xor(pz[z], 2);
    }
    float o = (c == 0) ? pz[0] : (c == 1) ? pz[1] : (c == 2) ? pz[2] : pz[3];
    float scale = exp2f(1.0f - (float)z_ptr[0]);
    out[(size_t)atom * 64 + lane] = o * scale;
}

extern "C" void kernel_launch(void* const* d_in, const int* in_sizes, int n_in,
                              void* d_out, int out_size, void* d_ws, size_t ws_size,
                              hipStream_t stream) {
    const int*   z_ptr    = (const int*)  d_in[0];
    const float* rij_unit = (const float*)d_in[2];
    const float* radial   = (const float*)d_in[3];
    const int*   atom_idx = (const int*)  d_in[4];
    const float* lambda_w = (const float*)d_in[5];
    const int*   lxlylz   = (const int*)  d_in[6];
    const int*   lsum     = (const int*)  d_in[7];
    const float* fact     = (const float*)d_in[8];

    const int npairs = in_sizes[4];
    const int nat    = out_size / (NRAD * NLAM);

    int* counts  = (int*)d_ws;            // nat ints (becomes scatter cursor)
    int* offsets = counts + nat;          // nat+1 ints
    int* perm    = offsets + nat + 1;     // npairs ints

    hipMemsetAsync(counts, 0, (size_t)nat * sizeof(int), stream);
    hist_kernel<<<(npairs + 255) / 256, 256, 0, stream>>>(atom_idx, counts, npairs);
    prefix_kernel<<<1, 1024, 0, stream>>>(counts, offsets, nat, npairs);
    scatter_kernel<<<(npairs + 255) / 256, 256, 0, stream>>>(atom_idx, counts, perm, npairs);
    reduce_kernel<<<(nat + 3) / 4, 256, 0, stream>>>(rij_unit, radial, lambda_w, lxlylz,
                                                     lsum, fact, offsets, perm, z_ptr,
                                                     (float*)d_out, nat);
}

// Round 3
// 82.864 us; speedup vs baseline: 1.5538x; 1.1776x over previous
//
#include <hip/hip_runtime.h>

#define NRAD 16
#define LL   34
#define NLAM 4
#define CH   32          // pairs staged per chunk per wave
#define G2S  21          // float2 stride per pair row (4 blocks*5 + extras slot 20)
#define RDS  17          // rad row stride (floats)

__global__ void hist_kernel(const int* __restrict__ idx, int* __restrict__ counts, int npairs) {
    int t = blockIdx.x * blockDim.x + threadIdx.x;
    int p = t * 4;
    if (p + 3 < npairs) {
        int4 v = *(const int4*)(idx + p);
        atomicAdd(&counts[v.x], 1); atomicAdd(&counts[v.y], 1);
        atomicAdd(&counts[v.z], 1); atomicAdd(&counts[v.w], 1);
    } else {
        for (int i = p; i < npairs; ++i) atomicAdd(&counts[idx[i]], 1);
    }
}

// 1-block scan: 16 elems/thread in registers, wave shuffle-scan, 2 barriers.
__global__ __launch_bounds__(1024) void prefix_kernel(int* __restrict__ counts,
                                                      int* __restrict__ offsets,
                                                      int nat, int npairs) {
    const int PT = 16;  // 1024*16 = 16384 >= nat
    __shared__ int wsum[16];
    int tid = threadIdx.x, lane = tid & 63, w = tid >> 6;
    int base = tid * PT;
    int c[PT];
    int s = 0;
#pragma unroll
    for (int k = 0; k < PT; ++k) {
        int i = base + k;
        c[k] = (i < nat) ? counts[i] : 0;
        s += c[k];
    }
    int incl = s;
#pragma unroll
    for (int off = 1; off < 64; off <<= 1) {
        int v = __shfl_up(incl, off);
        if (lane >= off) incl += v;
    }
    if (lane == 63) wsum[w] = incl;
    __syncthreads();
    if (tid == 0) {
        int run = 0;
        for (int i = 0; i < 16; ++i) { int t = wsum[i]; wsum[i] = run; run += t; }
    }
    __syncthreads();
    int excl = wsum[w] + incl - s;
#pragma unroll
    for (int k = 0; k < PT; ++k) {
        int i = base + k;
        if (i < nat) { offsets[i] = excl; counts[i] = excl; }
        excl += c[k];
    }
    if (tid == 0) offsets[nat] = npairs;
}

__global__ void scatter_kernel(const int* __restrict__ idx, int* __restrict__ cursor,
                               int* __restrict__ perm, int npairs) {
    int t = blockIdx.x * blockDim.x + threadIdx.x;
    int p = t * 4;
    if (p + 3 < npairs) {
        int4 v = *(const int4*)(idx + p);
        perm[atomicAdd(&cursor[v.x], 1)] = p;
        perm[atomicAdd(&cursor[v.y], 1)] = p + 1;
        perm[atomicAdd(&cursor[v.z], 1)] = p + 2;
        perm[atomicAdd(&cursor[v.w], 1)] = p + 3;
    } else {
        for (int i = p; i < npairs; ++i)
            perm[atomicAdd(&cursor[idx[i]], 1)] = i;
    }
}

// One wave per atom (4 waves/block, wave-private LDS, zero barriers in loop).
// Phase A: lane = staged pair; computes all 34 monomials (hardcoded recurrence
// matching _build_lxlylz(4) ordering), writes float2 to swizzled LDS.
// Phase B: lane (r=lane>>2, c=lane&3) accumulates its 8(+1) monomials over the
// staged pairs with conflict-free ds_reads; no shuffles in the loop.
__global__ __launch_bounds__(256) void reduce_kernel(
    const float* __restrict__ rij,
    const float* __restrict__ radial,
    const float* __restrict__ lambda_w,
    const int*   __restrict__ lsum,
    const float* __restrict__ fact,
    const int*   __restrict__ offsets,
    const int*   __restrict__ perm,
    const int*   __restrict__ z_ptr,
    float*       __restrict__ out,
    int nat)
{
    __shared__ float  coeff_sh[NLAM][LL];
    __shared__ float2 g2_sh[4][CH * G2S];
    __shared__ float  rad_sh[4][CH * RDS];
    __shared__ int    p_sh[4][CH];

    int tid = threadIdx.x;
    if (tid < NLAM * LL) {
        int z = tid / LL, l = tid - z * LL;
        float w = lambda_w[z];
        int   s = lsum[l];
        float pw = 1.0f;
        for (int i = 0; i < s; ++i) pw *= w;   // integer power: w may be negative
        coeff_sh[z][l] = pw * fact[l];
    }
    __syncthreads();

    int lane = tid & 63, wv = tid >> 6;
    int atom = blockIdx.x * 4 + wv;
    if (atom >= nat) return;

    int r = lane >> 2, c = lane & 3;
    int c5 = c * 5;

    float2* G2 = g2_sh[wv];
    float*  RD = rad_sh[wv];
    int*    PS = p_sh[wv];

    float a0=0,a1=0,a2=0,a3=0,a4=0,a5=0,a6=0,a7=0,aX=0;

    int beg = offsets[atom], end = offsets[atom + 1];

    for (int base = beg; base < end; base += CH) {
        int nn = min(CH, end - base);
        int pv = (lane < nn) ? perm[base + lane] : 0;
        if (lane < nn) PS[lane] = pv;

        // ---- phase A: monomials for own pair ----
        if (lane < nn) {
            const float* rp = rij + 3 * pv;
            float x = rp[0] + 1e-12f;
            float y = rp[1] + 1e-12f;
            float z = rp[2] + 1e-12f;
            float m[LL];
            m[0]=z;      m[1]=y;      m[2]=x;
            m[3]=z*m[0]; m[4]=y*m[0]; m[5]=y*m[1];
            m[6]=x*m[0]; m[7]=x*m[1]; m[8]=x*m[2];
            m[9]=z*m[3];  m[10]=y*m[3]; m[11]=y*m[4]; m[12]=y*m[5];
            m[13]=x*m[3]; m[14]=x*m[4]; m[15]=x*m[5];
            m[16]=x*m[6]; m[17]=x*m[7]; m[18]=x*m[8];
            m[19]=z*m[9];  m[20]=y*m[9];  m[21]=y*m[10]; m[22]=y*m[11]; m[23]=y*m[12];
            m[24]=x*m[9];  m[25]=x*m[10]; m[26]=x*m[11]; m[27]=x*m[12];
            m[28]=x*m[13]; m[29]=x*m[14]; m[30]=x*m[15];
            m[31]=x*m[16]; m[32]=x*m[17]; m[33]=x*m[18];
#pragma unroll
            for (int cc = 0; cc < 4; ++cc)
#pragma unroll
                for (int t = 0; t < 4; ++t)
                    G2[lane * G2S + cc * 5 + t] =
                        make_float2(m[cc * 8 + 2 * t], m[cc * 8 + 2 * t + 1]);
            G2[lane * G2S + 20] = make_float2(m[32], m[33]);
        }

        // ---- cooperative radial staging (coalesced 64B rows) ----
        {
            int e = lane & 15, qr = lane >> 4;
#pragma unroll
            for (int rep = 0; rep < CH / 4; ++rep) {
                int q = rep * 4 + qr;
                if (q < nn) RD[q * RDS + e] = radial[PS[q] * NRAD + e];
            }
        }

        // ---- phase B: accumulate (no shuffles, conflict-free reads) ----
#pragma unroll 2
        for (int q = 0; q < nn; ++q) {
            float  rad = RD[q * RDS + r];
            float2 g0 = G2[q * G2S + c5 + 0];
            float2 g1 = G2[q * G2S + c5 + 1];
            float2 g2 = G2[q * G2S + c5 + 2];
            float2 g3 = G2[q * G2S + c5 + 3];
            float2 ge = G2[q * G2S + 20];
            a0 += rad * g0.x; a1 += rad * g0.y;
            a2 += rad * g1.x; a3 += rad * g1.y;
            a4 += rad * g2.x; a5 += rad * g2.y;
            a6 += rad * g3.x; a7 += rad * g3.y;
            float gx = (c == 0) ? ge.x : ge.y;
            aX += (c < 2) ? rad * gx : 0.0f;
        }
    }

    // ---- epilogue ----
    float q0=a0*a0, q1=a1*a1, q2=a2*a2, q3=a3*a3,
          q4=a4*a4, q5=a5*a5, q6=a6*a6, q7=a7*a7, qX=aX*aX;
    int b = c * 8;
    float pz[NLAM];
#pragma unroll
    for (int z = 0; z < NLAM; ++z) {
        float acc = coeff_sh[z][b+0]*q0 + coeff_sh[z][b+1]*q1 +
                    coeff_sh[z][b+2]*q2 + coeff_sh[z][b+3]*q3 +
                    coeff_sh[z][b+4]*q4 + coeff_sh[z][b+5]*q5 +
                    coeff_sh[z][b+6]*q6 + coeff_sh[z][b+7]*q7;
        if (c < 2) acc += coeff_sh[z][32 + c] * qX;
        pz[z] = acc;
    }
#pragma unroll
    for (int z = 0; z < NLAM; ++z) {
        pz[z] += __shfl_xor(pz[z], 1);
        pz[z] += __shfl_xor(pz[z], 2);
    }
    float o = (c == 0) ? pz[0] : (c == 1) ? pz[1] : (c == 2) ? pz[2] : pz[3];
    float scale = exp2f(1.0f - (float)z_ptr[0]);
    out[(size_t)atom * 64 + lane] = o * scale;
}

extern "C" void kernel_launch(void* const* d_in, const int* in_sizes, int n_in,
                              void* d_out, int out_size, void* d_ws, size_t ws_size,
                              hipStream_t stream) {
    const int*   z_ptr    = (const int*)  d_in[0];
    const float* rij_unit = (const float*)d_in[2];
    const float* radial   = (const float*)d_in[3];
    const int*   atom_idx = (const int*)  d_in[4];
    const float* lambda_w = (const float*)d_in[5];
    const int*   lsum     = (const int*)  d_in[7];
    const float* fact     = (const float*)d_in[8];

    const int npairs = in_sizes[4];
    const int nat    = out_size / (NRAD * NLAM);

    int* counts  = (int*)d_ws;            // nat ints (becomes scatter cursor)
    int* offsets = counts + nat;          // nat+1 ints
    int* perm    = offsets + nat + 1;     // npairs ints

    hipMemsetAsync(counts, 0, (size_t)nat * sizeof(int), stream);
    int nt4 = (npairs + 3) / 4;
    hist_kernel<<<(nt4 + 255) / 256, 256, 0, stream>>>(atom_idx, counts, npairs);
    prefix_kernel<<<1, 1024, 0, stream>>>(counts, offsets, nat, npairs);
    scatter_kernel<<<(nt4 + 255) / 256, 256, 0, stream>>>(atom_idx, counts, perm, npairs);
    reduce_kernel<<<(nat + 3) / 4, 256, 0, stream>>>(rij_unit, radial, lambda_w,
                                                     lsum, fact, offsets, perm, z_ptr,
                                                     (float*)d_out, nat);
}